// Round 1
// baseline (4685.149 us; speedup 1.0000x reference)
//
#include <hip/hip_runtime.h>
#include <hip/hip_bf16.h>

#define N_NODES   100000
#define N_EDGES   1600000
#define NUM_GRAPHS 1000

typedef unsigned int u32;
typedef unsigned short u16;

__device__ __forceinline__ float bf2f(u16 u){ return __uint_as_float(((u32)u)<<16); }
// dual-dtype scalar load: isbf=1 -> bf16, else f32
__device__ __forceinline__ float ldf(const void* p, size_t i, int isbf){
  return isbf ? bf2f(((const u16*)p)[i]) : ((const float*)p)[i];
}

// ---------------- dtype detector ----------------
// If data is bf16, the LOW u16 of each u32 word is a bf16 value ~N(0,1):
// its exponent field (bits 14:7) lands in [110,137] essentially always.
// If data is f32, bits 14:7 are mid-mantissa bits -> ~uniform (~11% hit).
__global__ void k_detect(const u32* __restrict__ x, int* __restrict__ flag){
  int t = threadIdx.x; int cnt = 0;
  for (int i = t; i < 256; i += 64){
    u32 w = x[i];
    u32 e = (w >> 7) & 0xffu;
    if (e >= 110u && e <= 137u) cnt++;
  }
  for (int o = 32; o; o >>= 1) cnt += __shfl_xor(cnt, o);
  if (t == 0) *flag = (cnt > 128) ? 1 : 0;
}

// ---------------- fold edge embedding into msg linear ----------------
// fw2[l][j][c] = sum_k edge_W[j][k] * msg_W[l][64+k][c]   (16x64 per layer)
// fb[l][c]    = msg_b[l][c] + sum_k edge_b[k] * msg_W[l][64+k][c]
__global__ void k_prep(const void* __restrict__ eW, const void* __restrict__ eb,
                       const void* __restrict__ mW, const void* __restrict__ mb,
                       float* __restrict__ fw2, float* __restrict__ fb,
                       const int* __restrict__ flagp){
  int isbf = *flagp;
  int l = blockIdx.x, c = threadIdx.x;
  for (int j = 0; j < 16; j++){
    float acc = 0.f;
    for (int k = 0; k < 32; k++)
      acc += ldf(eW, (size_t)j*32 + k, isbf) * ldf(mW, (size_t)(l*96 + 64 + k)*64 + c, isbf);
    fw2[(l*16 + j)*64 + c] = acc;
  }
  float acc = ldf(mb, (size_t)l*64 + c, isbf);
  for (int k = 0; k < 32; k++)
    acc += ldf(eb, k, isbf) * ldf(mW, (size_t)(l*96 + 64 + k)*64 + c, isbf);
  fb[l*64 + c] = acc;
}

// ---------------- node embedding: h = x @ node_W + node_b ----------------
__global__ void k_node_emb(const void* __restrict__ x, const void* __restrict__ nW,
                           const void* __restrict__ nb, float* __restrict__ h,
                           const int* __restrict__ flagp){
  int isbf = *flagp;
  int lane = threadIdx.x & 63;
  int gw = (blockIdx.x*blockDim.x + threadIdx.x) >> 6;
  int nw = (gridDim.x*blockDim.x) >> 6;
  float w[32];
#pragma unroll
  for (int k = 0; k < 32; k++) w[k] = ldf(nW, (size_t)k*64 + lane, isbf);
  float bias = ldf(nb, lane, isbf);
  for (int n = gw; n < N_NODES; n += nw){
    float acc = bias;
    if (isbf){
      const uint4* xr = (const uint4*)((const u16*)x + (size_t)n*32);
#pragma unroll
      for (int q = 0; q < 4; q++){
        uint4 a = xr[q];
        u32 uu[4] = {a.x, a.y, a.z, a.w};
#pragma unroll
        for (int j = 0; j < 4; j++){
          acc = fmaf(__uint_as_float(uu[j] << 16),        w[q*8 + 2*j + 0], acc);
          acc = fmaf(__uint_as_float(uu[j] & 0xffff0000u), w[q*8 + 2*j + 1], acc);
        }
      }
    } else {
      const float4* xr = (const float4*)((const float*)x + (size_t)n*32);
#pragma unroll
      for (int q = 0; q < 8; q++){
        float4 a = xr[q];
        acc = fmaf(a.x, w[q*4+0], acc); acc = fmaf(a.y, w[q*4+1], acc);
        acc = fmaf(a.z, w[q*4+2], acc); acc = fmaf(a.w, w[q*4+3], acc);
      }
    }
    h[(size_t)n*64 + lane] = acc;
  }
}

// ---------------- in-degree ----------------
__global__ void k_deg(const int* __restrict__ ei, float* __restrict__ deg){
  int i = blockIdx.x*blockDim.x + threadIdx.x;
  int stride = gridDim.x*blockDim.x;
  for (int e = i; e < N_EDGES; e += stride)
    atomicAdd(&deg[ei[N_EDGES + e]], 1.0f);
}

// ---------------- message + raw aggregate + BN stats ----------------
// wave-per-edge, lane = output column. Weights in VGPRs, h[src] row read as
// wave-uniform float4 broadcasts, one coalesced 256B atomicAdd per edge.
__global__ void __launch_bounds__(256) k_msg(
    const float* __restrict__ h, const void* __restrict__ ea,
    const int* __restrict__ ei, const void* __restrict__ mW,
    const float* __restrict__ fw2, const float* __restrict__ fb,
    float* __restrict__ agg, float* __restrict__ stats,
    const int* __restrict__ flagp, int l){
  __shared__ float bs[128];
  if (threadIdx.x < 128) bs[threadIdx.x] = 0.f;
  __syncthreads();
  int isbf = *flagp;
  int lane = threadIdx.x & 63;
  int gw = (blockIdx.x*blockDim.x + threadIdx.x) >> 6;
  int nw = (gridDim.x*blockDim.x) >> 6;
  float w1[64];
#pragma unroll
  for (int k = 0; k < 64; k++) w1[k] = ldf(mW, (size_t)(l*96 + k)*64 + lane, isbf);
  float w2[16];
#pragma unroll
  for (int j = 0; j < 16; j++) w2[j] = fw2[(l*16 + j)*64 + lane];
  float bias = fb[l*64 + lane];
  float s1 = 0.f, s2 = 0.f;
  for (int e = gw; e < N_EDGES; e += nw){
    int src = ei[e], dst = ei[N_EDGES + e];
    const float4* hr = (const float4*)(h + (size_t)src*64);
    float m = bias;
#pragma unroll
    for (int q = 0; q < 16; q++){
      float4 hv = hr[q];
      m = fmaf(hv.x, w1[4*q+0], m); m = fmaf(hv.y, w1[4*q+1], m);
      m = fmaf(hv.z, w1[4*q+2], m); m = fmaf(hv.w, w1[4*q+3], m);
    }
    if (isbf){
      const uint4* er = (const uint4*)((const u16*)ea + (size_t)e*16);
#pragma unroll
      for (int q = 0; q < 2; q++){
        uint4 a = er[q];
        u32 uu[4] = {a.x, a.y, a.z, a.w};
#pragma unroll
        for (int j = 0; j < 4; j++){
          m = fmaf(__uint_as_float(uu[j] << 16),         w2[q*8 + 2*j + 0], m);
          m = fmaf(__uint_as_float(uu[j] & 0xffff0000u), w2[q*8 + 2*j + 1], m);
        }
      }
    } else {
      const float4* er = (const float4*)((const float*)ea + (size_t)e*16);
#pragma unroll
      for (int q = 0; q < 4; q++){
        float4 a = er[q];
        m = fmaf(a.x, w2[4*q+0], m); m = fmaf(a.y, w2[4*q+1], m);
        m = fmaf(a.z, w2[4*q+2], m); m = fmaf(a.w, w2[4*q+3], m);
      }
    }
    m = fmaxf(m, 0.f);
    atomicAdd(&agg[(size_t)dst*64 + lane], m);
    s1 += m;
    s2 = fmaf(m, m, s2);
  }
  atomicAdd(&bs[lane], s1);
  atomicAdd(&bs[64 + lane], s2);
  __syncthreads();
  if (threadIdx.x < 128) atomicAdd(&stats[threadIdx.x], bs[threadIdx.x]);
}

// ---------------- BN finalize: aff[c]=gamma*rs, aff[64+c]=beta-gamma*mu*rs ----
__global__ void k_fin(const float* __restrict__ stats, const void* __restrict__ gamma,
                      const void* __restrict__ beta, float* __restrict__ aff,
                      float cnt_inv, int goff, const int* __restrict__ flagp){
  int isbf = *flagp; int c = threadIdx.x;
  float mu  = stats[c]      * cnt_inv;
  float var = stats[64 + c] * cnt_inv - mu*mu;
  float rs  = rsqrtf(var + 1e-5f);
  float g = ldf(gamma, (size_t)goff + c, isbf);
  float b = ldf(beta,  (size_t)goff + c, isbf);
  aff[c]      = g*rs;
  aff[64 + c] = b - g*mu*rs;
}

// ---------------- update pass 1: r = h @ updW[0:64] + upd_b ----------------
__global__ void k_upd1(const float* __restrict__ h, const void* __restrict__ uW,
                       const void* __restrict__ ub, float* __restrict__ r,
                       const int* __restrict__ flagp, int l){
  int isbf = *flagp;
  int lane = threadIdx.x & 63;
  int gw = (blockIdx.x*blockDim.x + threadIdx.x) >> 6;
  int nw = (gridDim.x*blockDim.x) >> 6;
  float w[64];
#pragma unroll
  for (int k = 0; k < 64; k++) w[k] = ldf(uW, (size_t)(l*128 + k)*64 + lane, isbf);
  float bias = ldf(ub, (size_t)l*64 + lane, isbf);
  for (int n = gw; n < N_NODES; n += nw){
    const float4* hr = (const float4*)(h + (size_t)n*64);
    float acc = bias;
#pragma unroll
    for (int q = 0; q < 16; q++){
      float4 a = hr[q];
      acc = fmaf(a.x, w[4*q+0], acc); acc = fmaf(a.y, w[4*q+1], acc);
      acc = fmaf(a.z, w[4*q+2], acc); acc = fmaf(a.w, w[4*q+3], acc);
    }
    r[(size_t)n*64 + lane] = acc;
  }
}

// ---------------- update pass 2: r = relu(r + aggn @ updW[64:128]) + stats ----
// BN-of-messages folded into weights: w'[k] = s_k*W2[k][c], tv = sum_k t_k*W2[k][c]
__global__ void k_upd2(const float* __restrict__ agg, const float* __restrict__ deg,
                       const float* __restrict__ maff, const void* __restrict__ uW,
                       float* __restrict__ r, float* __restrict__ stats,
                       const int* __restrict__ flagp, int l){
  __shared__ float bs[128];
  if (threadIdx.x < 128) bs[threadIdx.x] = 0.f;
  __syncthreads();
  int isbf = *flagp;
  int lane = threadIdx.x & 63;
  int gw = (blockIdx.x*blockDim.x + threadIdx.x) >> 6;
  int nw = (gridDim.x*blockDim.x) >> 6;
  float w[64]; float tv = 0.f;
#pragma unroll
  for (int k = 0; k < 64; k++){
    float wk = ldf(uW, (size_t)(l*128 + 64 + k)*64 + lane, isbf);
    w[k] = wk * maff[k];
    tv = fmaf(maff[64 + k], wk, tv);
  }
  float s1 = 0.f, s2 = 0.f;
  for (int n = gw; n < N_NODES; n += nw){
    float dn = deg[n];
    const float4* ar = (const float4*)(agg + (size_t)n*64);
    float acc = fmaf(dn, tv, r[(size_t)n*64 + lane]);
#pragma unroll
    for (int q = 0; q < 16; q++){
      float4 a = ar[q];
      acc = fmaf(a.x, w[4*q+0], acc); acc = fmaf(a.y, w[4*q+1], acc);
      acc = fmaf(a.z, w[4*q+2], acc); acc = fmaf(a.w, w[4*q+3], acc);
    }
    float rl = fmaxf(acc, 0.f);
    r[(size_t)n*64 + lane] = rl;
    s1 += rl;
    s2 = fmaf(rl, rl, s2);
  }
  atomicAdd(&bs[lane], s1);
  atomicAdd(&bs[64 + lane], s2);
  __syncthreads();
  if (threadIdx.x < 128) atomicAdd(&stats[threadIdx.x], bs[threadIdx.x]);
}

// ---------------- node BN apply: h = s*r + t ----------------
__global__ void k_norm(const float* __restrict__ r, const float* __restrict__ uaff,
                       float* __restrict__ h){
  int i = blockIdx.x*blockDim.x + threadIdx.x;     // over N_NODES*16 float4s
  if (i >= N_NODES*16) return;
  int c4 = i & 15;
  float4 sq = *(const float4*)(uaff + 4*c4);
  float4 tq = *(const float4*)(uaff + 64 + 4*c4);
  float4 v = ((const float4*)r)[i];
  float4 o;
  o.x = fmaf(sq.x, v.x, tq.x); o.y = fmaf(sq.y, v.y, tq.y);
  o.z = fmaf(sq.z, v.z, tq.z); o.w = fmaf(sq.w, v.w, tq.w);
  ((float4*)h)[i] = o;
}

// ---------------- global add pool (batch is sorted -> run accumulation) ------
__global__ void k_pool(const float* __restrict__ h, const int* __restrict__ batch,
                       float* __restrict__ g){
  int lane = threadIdx.x & 63;
  int gw = (blockIdx.x*blockDim.x + threadIdx.x) >> 6;
  int nw = (gridDim.x*blockDim.x) >> 6;
  int chunk = (N_NODES + nw - 1) / nw;
  int n0 = gw*chunk;
  int n1 = n0 + chunk; if (n1 > N_NODES) n1 = N_NODES;
  int cur = -1; float acc = 0.f;
  for (int n = n0; n < n1; n++){
    int b = batch[n];
    float v = h[(size_t)n*64 + lane];
    if (b != cur){
      if (cur >= 0) atomicAdd(&g[(size_t)cur*64 + lane], acc);
      cur = b; acc = v;
    } else acc += v;
  }
  if (cur >= 0) atomicAdd(&g[(size_t)cur*64 + lane], acc);
}

// ---------------- readout: out = relu(g@r1+b1)@r2 + b2 ----------------
__global__ void k_read(const float* __restrict__ g, const void* __restrict__ r1W,
                       const void* __restrict__ r1b, const void* __restrict__ r2W,
                       const void* __restrict__ r2b, void* __restrict__ out,
                       const int* __restrict__ flagp){
  int isbf = *flagp;
  int lane = threadIdx.x;
  int gr = blockIdx.x;
  float w[64];
#pragma unroll
  for (int k = 0; k < 64; k++) w[k] = ldf(r1W, (size_t)k*64 + lane, isbf);
  float acc = ldf(r1b, lane, isbf);
  const float4* grow = (const float4*)(g + (size_t)gr*64);
#pragma unroll
  for (int q = 0; q < 16; q++){
    float4 a = grow[q];
    acc = fmaf(a.x, w[4*q+0], acc); acc = fmaf(a.y, w[4*q+1], acc);
    acc = fmaf(a.z, w[4*q+2], acc); acc = fmaf(a.w, w[4*q+3], acc);
  }
  float hid = fmaxf(acc, 0.f);
  float p = hid * ldf(r2W, lane, isbf);
  for (int o = 32; o; o >>= 1) p += __shfl_xor(p, o);
  if (lane == 0){
    float v = p + ldf(r2b, 0, isbf);
    if (isbf) ((__hip_bfloat16*)out)[gr] = __float2bfloat16(v);
    else      ((float*)out)[gr] = v;
  }
}

extern "C" void kernel_launch(void* const* d_in, const int* in_sizes, int n_in,
                              void* d_out, int out_size, void* d_ws, size_t ws_size,
                              hipStream_t stream){
  const void* x    = d_in[0];
  const void* ea   = d_in[1];
  const int*  ei   = (const int*)d_in[2];
  const int*  bt   = (const int*)d_in[3];
  const void* nW   = d_in[4];  const void* nb  = d_in[5];
  const void* eW   = d_in[6];  const void* eb  = d_in[7];
  const void* mW   = d_in[8];  const void* mb  = d_in[9];
  const void* mg   = d_in[10]; const void* mbe = d_in[11];
  const void* uW   = d_in[12]; const void* ub  = d_in[13];
  const void* ug   = d_in[14]; const void* ube = d_in[15];
  const void* r1W  = d_in[16]; const void* r1b = d_in[17];
  const void* r2W  = d_in[18]; const void* r2b = d_in[19];

  float* ws = (float*)d_ws;
  float* h      = ws + 0;          // 6,400,000
  float* r      = ws + 6400000;    // 6,400,000
  float* deg    = ws + 12800000;   // 100,000
  float* g      = ws + 12900000;   // 64,000
  int*   flag   = (int*)(ws + 12964000);
  float* fw2    = ws + 12964016;   // 3*16*64
  float* fb     = ws + 12967088;   // 3*64
  float* agg    = ws + 12967280;   // 6,400,000  (contiguous with stats for one memset)
  float* mstats = ws + 19367280;   // 128
  float* ustats = ws + 19367408;   // 128
  float* maff   = ws + 19367536;   // 128
  float* uaff   = ws + 19367664;   // 128

  k_detect<<<1, 64, 0, stream>>>((const u32*)x, flag);
  hipMemsetAsync(deg, 0, (100000 + 64000)*sizeof(float), stream);   // deg + g
  k_prep<<<3, 64, 0, stream>>>(eW, eb, mW, mb, fw2, fb, flag);
  k_node_emb<<<256, 256, 0, stream>>>(x, nW, nb, h, flag);
  k_deg<<<512, 256, 0, stream>>>(ei, deg);

  for (int l = 0; l < 3; l++){
    hipMemsetAsync(agg, 0, (6400000 + 256)*sizeof(float), stream);  // agg + mstats + ustats
    k_msg<<<1024, 256, 0, stream>>>(h, ea, ei, mW, fw2, fb, agg, mstats, flag, l);
    k_fin<<<1, 64, 0, stream>>>(mstats, mg, mbe, maff, 1.0f/(float)N_EDGES, l*64, flag);
    k_upd1<<<256, 256, 0, stream>>>(h, uW, ub, r, flag, l);
    k_upd2<<<256, 256, 0, stream>>>(agg, deg, maff, uW, r, ustats, flag, l);
    k_fin<<<1, 64, 0, stream>>>(ustats, ug, ube, uaff, 1.0f/(float)N_NODES, l*64, flag);
    k_norm<<<(N_NODES*16 + 255)/256, 256, 0, stream>>>(r, uaff, h);
  }

  k_pool<<<128, 256, 0, stream>>>(h, bt, g);
  k_read<<<NUM_GRAPHS, 64, 0, stream>>>(g, r1W, r1b, r2W, r2b, d_out, flag);
}